// Round 3
// baseline (588.026 us; speedup 1.0000x reference)
//
#include <hip/hip_runtime.h>

// AdaConv: instance-norm -> per-sample 3x3 conv -> per-sample 1x1 conv + bias
//          -> shared 3x3 conv. Reflect-pad(1), NHWC. B=16, H=W=64, C=256.
// Norm folded into conv1: conv(xn,W) = conv(x, rstd*W) - sum(mean*rstd*W).
// Input dtype (fp32 vs bf16) detected at runtime; OUTPUT IS ALWAYS FP32.

typedef __bf16 bf16x8 __attribute__((ext_vector_type(8)));
typedef float f32x4 __attribute__((ext_vector_type(4)));

__device__ __forceinline__ float bf2f(unsigned short v) {
    return __uint_as_float(((unsigned int)v) << 16);
}
__device__ __forceinline__ unsigned short f2bf(float f) {
    unsigned int u = __float_as_uint(f);
    unsigned int r = (u + 0x7FFFu + ((u >> 16) & 1u)) >> 16;  // RNE
    return (unsigned short)r;
}
__device__ __forceinline__ float ldg_elem(const void* p, size_t idx, bool isbf) {
    return isbf ? bf2f(((const unsigned short*)p)[idx]) : ((const float*)p)[idx];
}

// ---------------- dtype detection ----------------
// fp32 data read as bf16 shorts: ~half decode to wild magnitudes/NaN.
// genuine bf16 N(0,1) data: essentially none do.
__global__ void detect_dtype(const unsigned short* __restrict__ x, int* __restrict__ flag) {
    __shared__ int wild;
    if (threadIdx.x == 0) wild = 0;
    __syncthreads();
    int cnt = 0;
    for (int i = 0; i < 16; ++i) {
        float a = fabsf(bf2f(x[threadIdx.x * 16 + i]));
        if (!(a < 64.f) || (a != 0.f && a < 1e-5f)) cnt++;  // catches NaN/Inf too
    }
    atomicAdd(&wild, cnt);
    __syncthreads();
    if (threadIdx.x == 0) *flag = (wild > 512) ? 0 : 1;  // 0 = fp32, 1 = bf16
}

// ---------------- instance-norm stats ----------------

__global__ void init_stats(float* s) {  // grid 32: zeros ssum(4096)+ssq(4096)
    s[blockIdx.x * 256 + threadIdx.x] = 0.f;
}

// grid (16 batches, 16 spatial chunks), block 256 (one lane per channel)
__global__ void norm_partial(const void* __restrict__ x, const int* __restrict__ flag,
                             float* __restrict__ ssum, float* __restrict__ ssq) {
    const bool isbf = (*flag != 0);
    const int b = blockIdx.x, chunk = blockIdx.y, c = threadIdx.x;
    const size_t base = ((size_t)(b * 4096 + chunk * 256)) * 256 + c;
    float s = 0.f, q = 0.f;
    for (int i = 0; i < 256; ++i) {
        float v = ldg_elem(x, base + (size_t)i * 256, isbf);
        s += v; q += v * v;
    }
    atomicAdd(&ssum[b * 256 + c], s);
    atomicAdd(&ssq[b * 256 + c], q);
}

__global__ void norm_finalize(float* ssum, float* ssq) {
    int i = blockIdx.x * 256 + threadIdx.x;
    float mean = ssum[i] * (1.f / 4096.f);
    float var  = ssq[i]  * (1.f / 4096.f) - mean * mean;
    ssum[i] = mean;                 // becomes mean[]
    ssq[i]  = rsqrtf(var + 1e-3f);  // becomes rstd[]
}

// ---------------- weight transpose: [slice][ci][co] -> [b][co][s*256+ci] ----------------
// grid (nslices, 4, 4) of 64x64 tiles, block 256. SCALE: multiply by rstd[b][ci].
template <bool SCALE>
__global__ void transpose_wk(const void* __restrict__ src, const int* __restrict__ flag,
                             unsigned short* __restrict__ dst,
                             int s_per, long dstBStride, int coStride,
                             const float* __restrict__ rstd) {
    __shared__ unsigned short tile[64][66];
    const bool isbf = (*flag != 0);
    const int sl = blockIdx.x;
    const int b = sl / s_per;
    const size_t dbase = (size_t)b * (size_t)dstBStride + (size_t)(sl % s_per) * 256;
    const int ci0 = blockIdx.y * 64, co0 = blockIdx.z * 64;
    const int tx = threadIdx.x & 63, ty = threadIdx.x >> 6;  // ty in [0,4)
#pragma unroll
    for (int i = 0; i < 16; ++i) {
        int ci = ty + i * 4;
        size_t sidx = (size_t)sl * 65536 + (size_t)(ci0 + ci) * 256 + co0 + tx;
        tile[ci][tx] = isbf ? ((const unsigned short*)src)[sidx]
                            : f2bf(((const float*)src)[sidx]);
    }
    __syncthreads();
    const float sc = SCALE ? rstd[b * 256 + ci0 + tx] : 1.f;
#pragma unroll
    for (int i = 0; i < 16; ++i) {
        int co = ty + i * 4;
        unsigned short v = tile[tx][co];
        if (SCALE) v = f2bf(bf2f(v) * sc);
        dst[dbase + (size_t)(co0 + co) * coStride + ci0 + tx] = v;
    }
}

// ---------------- correction bias: negcorr[b][co] = -sum_k mean[b][ci(k)] * dkT[b][co][k]
// grid (16, 64), block 256 = 4 waves; one wave per (b, co).
__global__ void corr_kernel(const unsigned short* __restrict__ dkT,
                            const float* __restrict__ mean,
                            float* __restrict__ negcorr) {
    const int b = blockIdx.x;
    const int lane = threadIdx.x & 63;
    const int co = blockIdx.y * 4 + (threadIdx.x >> 6);
    const unsigned short* wp = dkT + (size_t)(b * 256 + co) * 2304;
    const float* mb = mean + b * 256;
    const int ci0 = (lane & 31) * 8;  // k % 256 repeats per 512-chunk
    float4 ma = *(const float4*)(mb + ci0);
    float4 mc = *(const float4*)(mb + ci0 + 4);
    float mm[8] = {ma.x, ma.y, ma.z, ma.w, mc.x, mc.y, mc.z, mc.w};
    float sum = 0.f;
#pragma unroll
    for (int c = 0; c < 5; ++c) {
        int k = c * 512 + lane * 8;
        if (k < 2304) {
            uint4 w = *(const uint4*)(wp + k);
            unsigned int wsv[4] = {w.x, w.y, w.z, w.w};
#pragma unroll
            for (int j = 0; j < 4; ++j) {
                sum += bf2f((unsigned short)(wsv[j] & 0xFFFF)) * mm[2 * j];
                sum += bf2f((unsigned short)(wsv[j] >> 16)) * mm[2 * j + 1];
            }
        }
    }
#pragma unroll
    for (int off = 32; off > 0; off >>= 1) sum += __shfl_down(sum, off);
    if (lane == 0) negcorr[b * 256 + co] = -sum;
}

// ---------------- implicit-GEMM conv (MFMA) ----------------
// Per batch: C[M=4096][N=256] = A[M][K] * B[K][N], K = KSLICES*256.
// Tile 128x128, BK=32, 4 waves each computing a 64x64 quadrant (4x4 mfma 16x16x32).
// BIAS_MODE: 0=none, 1=fp32 internal, 2=input per-sample, 3=input shared.
// SRC_ADAPT: src is an input (fp32/bf16 per flag); else internal bf16.
// OUT_F32: write fp32 (final output); else internal bf16.
template <int KSLICES, bool PER_SAMPLE_W, int BIAS_MODE, bool IS3X3, bool SRC_ADAPT, bool OUT_F32>
__global__ __launch_bounds__(256) void gemm_conv(const void* __restrict__ src,
                                                 const int* __restrict__ flag,
                                                 const unsigned short* __restrict__ wT,
                                                 const void* __restrict__ bias,
                                                 void* __restrict__ dst) {
    constexpr int KTOT = KSLICES * 256;
    __shared__ unsigned short As[128][40];  // rows padded 32->40 (80B = 5*16B, aligned)
    __shared__ unsigned short Bs[128][40];

    const bool in_bf = (SRC_ADAPT || BIAS_MODE >= 2) ? (*flag != 0) : true;
    const int t = threadIdx.x;
    const int b = blockIdx.z;
    const int m0 = blockIdx.x * 128;
    const int n0 = blockIdx.y * 128;
    const size_t srcOfs = (size_t)b * (4096 * 256);
    const unsigned short* wB = wT + (PER_SAMPLE_W ? (size_t)b * 256 * KTOT : (size_t)0);

    f32x4 acc[4][4];
#pragma unroll
    for (int i = 0; i < 4; ++i)
#pragma unroll
        for (int j = 0; j < 4; ++j) acc[i][j] = (f32x4){0.f, 0.f, 0.f, 0.f};

    const int lane = t & 63;
    const int wave = t >> 6;
    const int rm = (wave >> 1) * 64;
    const int cn = (wave & 1) * 64;
    const int fr = lane & 15;
    const int kg = (lane >> 4) * 8;

    for (int kk = 0; kk < KTOT / 32; ++kk) {
        const int k0 = kk * 32;
        const int s = k0 >> 8;
        const int ci0 = k0 & 255;
        const int dh = IS3X3 ? (s / 3) - 1 : 0;
        const int dw = IS3X3 ? (s % 3) - 1 : 0;
        __syncthreads();
        // stage A: 128 rows x 32 k; 8 elems per chunk, 2 chunks/thread
#pragma unroll
        for (int cc = 0; cc < 2; ++cc) {
            int ch = t + cc * 256;
            int r = ch >> 2;
            int ko = (ch & 3) << 3;
            int m = m0 + r;
            int h = m >> 6, w = m & 63;
            if (IS3X3) {
                h += dh; h = (h < 0) ? 1 : (h > 63 ? 62 : h);  // reflect pad 1
                w += dw; w = (w < 0) ? 1 : (w > 63 ? 62 : w);
            }
            size_t eidx = srcOfs + (size_t)((h << 6) + w) * 256 + ci0 + ko;
            if (!SRC_ADAPT || in_bf) {
                uint4 v = *(const uint4*)((const unsigned short*)src + eidx);
                *(uint4*)&As[r][ko] = v;
            } else {
                const float* sf = (const float*)src + eidx;
                float4 f0 = *(const float4*)sf;
                float4 f1 = *(const float4*)(sf + 4);
                uint4 v;
                v.x = (unsigned int)f2bf(f0.x) | ((unsigned int)f2bf(f0.y) << 16);
                v.y = (unsigned int)f2bf(f0.z) | ((unsigned int)f2bf(f0.w) << 16);
                v.z = (unsigned int)f2bf(f1.x) | ((unsigned int)f2bf(f1.y) << 16);
                v.w = (unsigned int)f2bf(f1.z) | ((unsigned int)f2bf(f1.w) << 16);
                *(uint4*)&As[r][ko] = v;
            }
        }
        // stage B: 128 co x 32 k from [co][k] layout (contiguous along k)
#pragma unroll
        for (int cc = 0; cc < 2; ++cc) {
            int ch = t + cc * 256;
            int n = ch >> 2;
            int ko = (ch & 3) << 3;
            uint4 v = *(const uint4*)(wB + (size_t)(n0 + n) * KTOT + k0 + ko);
            *(uint4*)&Bs[n][ko] = v;
        }
        __syncthreads();

        bf16x8 af[4], bfr[4];
#pragma unroll
        for (int i = 0; i < 4; ++i) af[i] = *(const bf16x8*)&As[rm + i * 16 + fr][kg];
#pragma unroll
        for (int j = 0; j < 4; ++j) bfr[j] = *(const bf16x8*)&Bs[cn + j * 16 + fr][kg];
#pragma unroll
        for (int i = 0; i < 4; ++i)
#pragma unroll
            for (int j = 0; j < 4; ++j)
                acc[i][j] = __builtin_amdgcn_mfma_f32_16x16x32_bf16(af[i], bfr[j], acc[i][j], 0, 0, 0);
    }

    // epilogue: C/D layout col=lane&15, row=(lane>>4)*4+reg
    const int rbase = (lane >> 4) * 4;
    const int col = lane & 15;
    float bv[4];
#pragma unroll
    for (int j = 0; j < 4; ++j) {
        int n = n0 + cn + j * 16 + col;
        if (BIAS_MODE == 1)      bv[j] = ((const float*)bias)[b * 256 + n];
        else if (BIAS_MODE == 2) bv[j] = ldg_elem(bias, b * 256 + n, in_bf);
        else if (BIAS_MODE == 3) bv[j] = ldg_elem(bias, n, in_bf);
        else                     bv[j] = 0.f;
    }
#pragma unroll
    for (int i = 0; i < 4; ++i) {
#pragma unroll
        for (int rr = 0; rr < 4; ++rr) {
            int m = m0 + rm + i * 16 + rbase + rr;
            size_t rowoff = ((size_t)b * 4096 + m) * 256;
#pragma unroll
            for (int j = 0; j < 4; ++j) {
                int n = n0 + cn + j * 16 + col;
                float val = acc[i][j][rr] + bv[j];
                if (OUT_F32) ((float*)dst)[rowoff + n] = val;
                else         ((unsigned short*)dst)[rowoff + n] = f2bf(val);
            }
        }
    }
}

extern "C" void kernel_launch(void* const* d_in, const int* in_sizes, int n_in,
                              void* d_out, int out_size, void* d_ws, size_t ws_size,
                              hipStream_t stream) {
    const void* x    = d_in[0];  // [16,64,64,256]
    const void* dk   = d_in[1];  // [16,3,3,256,256]
    const void* pk   = d_in[2];  // [16,1,1,256,256]
    const void* bias = d_in[3];  // [16,256]
    const void* cw   = d_in[4];  // [3,3,256,256]
    const void* cb   = d_in[5];  // [256]

    // workspace layout (36,896,768 bytes):
    //   0        flag        (int)
    //   1024     mean/ssum   16 KB
    //   17408    rstd/ssq    16 KB
    //   33792    negcorr     16 KB (fp32)
    //   65536    pkT         2,097,152   [16][256][256]
    //   2162688  cwT         1,179,648   [256][2304]
    //   3342336  dkT         18,874,368  [16][256][2304] (dead after conv1)
    //   3342336  y2          33,554,432  (bf16; overlaps dkT, written after conv1)
    const size_t NEED = 3342336u + 33554432u;
    if (ws_size < NEED) return;  // diagnostic: leaves out==0 -> absmax ~4.78

    char* ws = (char*)d_ws;
    int*   flagp   = (int*)ws;
    float* meanp   = (float*)(ws + 1024);
    float* rstdp   = (float*)(ws + 17408);
    float* negcorr = (float*)(ws + 33792);
    unsigned short* pkT = (unsigned short*)(ws + 65536);
    unsigned short* cwT = (unsigned short*)(ws + 2162688);
    unsigned short* dkT = (unsigned short*)(ws + 3342336);
    unsigned short* y2  = (unsigned short*)(ws + 3342336);
    unsigned short* y1  = (unsigned short*)d_out;  // bf16 scratch inside fp32 out buffer

    detect_dtype<<<1, 256, 0, stream>>>((const unsigned short*)x, flagp);

    // instance-norm stats
    init_stats<<<32, 256, 0, stream>>>(meanp);
    norm_partial<<<dim3(16, 16), 256, 0, stream>>>(x, flagp, meanp, rstdp);
    norm_finalize<<<16, 256, 0, stream>>>(meanp, rstdp);

    // weight transposes to [co][k] (dk rows scaled by rstd)
    transpose_wk<true ><<<dim3(144, 4, 4), 256, 0, stream>>>(dk, flagp, dkT, 9, 589824L, 2304, rstdp);
    transpose_wk<false><<<dim3(16, 4, 4), 256, 0, stream>>>(pk, flagp, pkT, 1, 65536L, 256, nullptr);
    transpose_wk<false><<<dim3(9, 4, 4), 256, 0, stream>>>(cw, flagp, cwT, 9, 0L, 2304, nullptr);

    // fp32 correction bias for folded norm
    corr_kernel<<<dim3(16, 64), 256, 0, stream>>>(dkT, meanp, negcorr);

    // conv1: per-sample 3x3 on raw x (adaptive dtype) + negcorr bias -> y1 (bf16 in d_out)
    gemm_conv<9, true, 1, true, true, false><<<dim3(32, 2, 16), 256, 0, stream>>>(x, flagp, dkT, negcorr, y1);
    // pointwise 1x1 + per-sample bias -> y2 (bf16, ws)
    gemm_conv<1, true, 2, false, false, false><<<dim3(32, 2, 16), 256, 0, stream>>>(y1, flagp, pkT, bias, y2);
    // shared 3x3 + conv_b -> out (fp32)
    gemm_conv<9, false, 3, true, false, true><<<dim3(32, 2, 16), 256, 0, stream>>>(y2, flagp, cwT, cb, d_out);
}

// Round 4
// 484.663 us; speedup vs baseline: 1.2133x; 1.2133x over previous
//
#include <hip/hip_runtime.h>

// AdaConv: instance-norm -> per-sample 3x3 conv -> per-sample 1x1 conv + bias
//          -> shared 3x3 conv. Reflect-pad(1), NHWC. B=16, H=W=64, C=256.
// Inputs fp32 (runtime-detected vs bf16); OUTPUT FP32. Internal compute bf16 MFMA.
// Big-ws path: explicit norm_apply -> xn(bf16), all GEMMs use global_load_lds DMA.
// Small-ws fallback: norm folded into conv1 weights (Round-3 register-staging conv1).

typedef __bf16 bf16x8 __attribute__((ext_vector_type(8)));
typedef float f32x4 __attribute__((ext_vector_type(4)));

__device__ __forceinline__ float bf2f(unsigned short v) {
    return __uint_as_float(((unsigned int)v) << 16);
}
__device__ __forceinline__ unsigned short f2bf(float f) {
    unsigned int u = __float_as_uint(f);
    unsigned int r = (u + 0x7FFFu + ((u >> 16) & 1u)) >> 16;  // RNE
    return (unsigned short)r;
}
__device__ __forceinline__ float ldg_elem(const void* p, size_t idx, bool isbf) {
    return isbf ? bf2f(((const unsigned short*)p)[idx]) : ((const float*)p)[idx];
}

// async global->LDS DMA, 16B per lane; LDS dest = wave-uniform base + lane*16
__device__ __forceinline__ void gload16(const void* g, void* l) {
    __builtin_amdgcn_global_load_lds(
        (__attribute__((address_space(1))) void*)(unsigned long long)g,
        (__attribute__((address_space(3))) void*)(unsigned long long)l,
        16, 0, 0);
}

// ---------------- dtype detection ----------------
__global__ void detect_dtype(const unsigned short* __restrict__ x, int* __restrict__ flag) {
    __shared__ int wild;
    if (threadIdx.x == 0) wild = 0;
    __syncthreads();
    int cnt = 0;
    for (int i = 0; i < 16; ++i) {
        float a = fabsf(bf2f(x[threadIdx.x * 16 + i]));
        if (!(a < 64.f) || (a != 0.f && a < 1e-5f)) cnt++;  // catches NaN/Inf too
    }
    atomicAdd(&wild, cnt);
    __syncthreads();
    if (threadIdx.x == 0) *flag = (wild > 512) ? 0 : 1;  // 0 = fp32, 1 = bf16
}

// ---------------- instance-norm stats ----------------

__global__ void init_stats(float* s) { s[blockIdx.x * 256 + threadIdx.x] = 0.f; }

__global__ void norm_partial(const void* __restrict__ x, const int* __restrict__ flag,
                             float* __restrict__ ssum, float* __restrict__ ssq) {
    const bool isbf = (*flag != 0);
    const int b = blockIdx.x, chunk = blockIdx.y, c = threadIdx.x;
    const size_t base = ((size_t)(b * 4096 + chunk * 256)) * 256 + c;
    float s = 0.f, q = 0.f;
    for (int i = 0; i < 256; ++i) {
        float v = ldg_elem(x, base + (size_t)i * 256, isbf);
        s += v; q += v * v;
    }
    atomicAdd(&ssum[b * 256 + c], s);
    atomicAdd(&ssq[b * 256 + c], q);
}

__global__ void norm_finalize(float* ssum, float* ssq) {
    int i = blockIdx.x * 256 + threadIdx.x;
    float mean = ssum[i] * (1.f / 4096.f);
    float var  = ssq[i]  * (1.f / 4096.f) - mean * mean;
    ssum[i] = mean;
    ssq[i]  = rsqrtf(var + 1e-3f);
}

// normalize x -> bf16 xn. grid 8192 x 256, 8 elems/thread.
__global__ void norm_apply(const void* __restrict__ x, const int* __restrict__ flag,
                           const float* __restrict__ mean, const float* __restrict__ rstd,
                           unsigned short* __restrict__ xn) {
    const bool isbf = (*flag != 0);
    size_t e = ((size_t)blockIdx.x * 256 + threadIdx.x) * 8;
    int c0 = (int)(e & 255);
    int bc = (int)(e >> 20) * 256 + c0;
    float v[8];
    if (isbf) {
        uint4 raw = *(const uint4*)((const unsigned short*)x + e);
        unsigned int rr[4] = {raw.x, raw.y, raw.z, raw.w};
#pragma unroll
        for (int i = 0; i < 4; ++i) {
            v[2 * i]     = bf2f((unsigned short)(rr[i] & 0xFFFF));
            v[2 * i + 1] = bf2f((unsigned short)(rr[i] >> 16));
        }
    } else {
        float4 f0 = *(const float4*)((const float*)x + e);
        float4 f1 = *(const float4*)((const float*)x + e + 4);
        v[0] = f0.x; v[1] = f0.y; v[2] = f0.z; v[3] = f0.w;
        v[4] = f1.x; v[5] = f1.y; v[6] = f1.z; v[7] = f1.w;
    }
    unsigned int o[4];
#pragma unroll
    for (int i = 0; i < 4; ++i) {
        unsigned short lo = f2bf((v[2 * i]     - mean[bc + 2 * i])     * rstd[bc + 2 * i]);
        unsigned short hi = f2bf((v[2 * i + 1] - mean[bc + 2 * i + 1]) * rstd[bc + 2 * i + 1]);
        o[i] = (unsigned int)lo | ((unsigned int)hi << 16);
    }
    uint4 out; out.x = o[0]; out.y = o[1]; out.z = o[2]; out.w = o[3];
    *(uint4*)(xn + e) = out;
}

// ---------------- weight transpose: [slice][ci][co] -> [b][co][s*256+ci] ----------------
template <bool SCALE>
__global__ void transpose_wk(const void* __restrict__ src, const int* __restrict__ flag,
                             unsigned short* __restrict__ dst,
                             int s_per, long dstBStride, int coStride,
                             const float* __restrict__ rstd) {
    __shared__ unsigned short tile[64][66];
    const bool isbf = (*flag != 0);
    const int sl = blockIdx.x;
    const int b = sl / s_per;
    const size_t dbase = (size_t)b * (size_t)dstBStride + (size_t)(sl % s_per) * 256;
    const int ci0 = blockIdx.y * 64, co0 = blockIdx.z * 64;
    const int tx = threadIdx.x & 63, ty = threadIdx.x >> 6;
#pragma unroll
    for (int i = 0; i < 16; ++i) {
        int ci = ty + i * 4;
        size_t sidx = (size_t)sl * 65536 + (size_t)(ci0 + ci) * 256 + co0 + tx;
        tile[ci][tx] = isbf ? ((const unsigned short*)src)[sidx]
                            : f2bf(((const float*)src)[sidx]);
    }
    __syncthreads();
    const float sc = SCALE ? rstd[b * 256 + ci0 + tx] : 1.f;
#pragma unroll
    for (int i = 0; i < 16; ++i) {
        int co = ty + i * 4;
        unsigned short v = tile[tx][co];
        if (SCALE) v = f2bf(bf2f(v) * sc);
        dst[dbase + (size_t)(co0 + co) * coStride + ci0 + tx] = v;
    }
}

// ---------------- correction bias (small-ws fallback): negcorr[b][co] ----------------
__global__ void corr_kernel(const unsigned short* __restrict__ dkT,
                            const float* __restrict__ mean,
                            float* __restrict__ negcorr) {
    const int b = blockIdx.x;
    const int lane = threadIdx.x & 63;
    const int co = blockIdx.y * 4 + (threadIdx.x >> 6);
    const unsigned short* wp = dkT + (size_t)(b * 256 + co) * 2304;
    const float* mb = mean + b * 256;
    const int ci0 = (lane & 31) * 8;
    float4 ma = *(const float4*)(mb + ci0);
    float4 mc = *(const float4*)(mb + ci0 + 4);
    float mm[8] = {ma.x, ma.y, ma.z, ma.w, mc.x, mc.y, mc.z, mc.w};
    float sum = 0.f;
#pragma unroll
    for (int c = 0; c < 5; ++c) {
        int k = c * 512 + lane * 8;
        if (k < 2304) {
            uint4 w = *(const uint4*)(wp + k);
            unsigned int wsv[4] = {w.x, w.y, w.z, w.w};
#pragma unroll
            for (int j = 0; j < 4; ++j) {
                sum += bf2f((unsigned short)(wsv[j] & 0xFFFF)) * mm[2 * j];
                sum += bf2f((unsigned short)(wsv[j] >> 16)) * mm[2 * j + 1];
            }
        }
    }
#pragma unroll
    for (int off = 32; off > 0; off >>= 1) sum += __shfl_down(sum, off);
    if (lane == 0) negcorr[b * 256 + co] = -sum;
}

// ---------------- implicit-GEMM conv, DMA staging (global_load_lds w=16) ----------------
// src MUST be bf16. Tile 128x128, BK=32. Unpadded LDS [128][32] (DMA layout constraint).
// BIAS_MODE: 0=none, 2=input per-sample, 3=input shared.
template <int KSLICES, bool PER_SAMPLE_W, int BIAS_MODE, bool IS3X3, bool OUT_F32>
__global__ __launch_bounds__(256) void gemm_conv_dma(const unsigned short* __restrict__ src,
                                                     const int* __restrict__ flag,
                                                     const unsigned short* __restrict__ wT,
                                                     const void* __restrict__ bias,
                                                     void* __restrict__ dst) {
    constexpr int KTOT = KSLICES * 256;
    __shared__ unsigned short As[128 * 32];
    __shared__ unsigned short Bs[128 * 32];

    const int t = threadIdx.x;
    const int lane = t & 63;
    const int wave = t >> 6;
    const int b = blockIdx.z;
    const int m0 = blockIdx.x * 128;
    const int n0 = blockIdx.y * 128;
    const unsigned short* srcB = src + (size_t)b * (4096 * 256);
    const unsigned short* wB = wT + (PER_SAMPLE_W ? (size_t)b * 256 * KTOT : (size_t)0);
    const bool in_bf = (BIAS_MODE >= 2) ? (*flag != 0) : true;

    f32x4 acc[4][4];
#pragma unroll
    for (int i = 0; i < 4; ++i)
#pragma unroll
        for (int j = 0; j < 4; ++j) acc[i][j] = (f32x4){0.f, 0.f, 0.f, 0.f};

    // staging geometry: each wave-issue covers 16 rows (lane>>2) x 4 chunks (lane&3)
    const int lr = lane >> 2;
    const int lko = (lane & 3) * 8;
    const int rA0 = wave * 16 + lr;        // A issue 0 rows [wave*16, +16)
    const int rA1 = 64 + wave * 16 + lr;   // A issue 1 rows [64+wave*16, +16)
    unsigned short* ldsA0 = As + (wave * 16) * 32;        // wave-uniform bases
    unsigned short* ldsA1 = As + (64 + wave * 16) * 32;
    unsigned short* ldsB0 = Bs + (wave * 16) * 32;
    unsigned short* ldsB1 = Bs + (64 + wave * 16) * 32;

    const int mA0 = m0 + rA0, mA1 = m0 + rA1;
    const int h0a = mA0 >> 6, w0a = mA0 & 63;
    const int h1a = mA1 >> 6, w1a = mA1 & 63;
    const unsigned short* gB0 = wB + (size_t)(n0 + wave * 16 + lr) * KTOT + lko;
    const unsigned short* gB1 = wB + (size_t)(n0 + 64 + wave * 16 + lr) * KTOT + lko;

    const int fr = lane & 15;
    const int kg = (lane >> 4) * 8;
    const int rm = (wave >> 1) * 64;
    const int cn = (wave & 1) * 64;

    for (int s = 0; s < KSLICES; ++s) {
        int dh = IS3X3 ? (s / 3) - 1 : 0;
        int dw = IS3X3 ? (s % 3) - 1 : 0;
        int hh0 = h0a + dh; hh0 = (hh0 < 0) ? 1 : (hh0 > 63 ? 62 : hh0);
        int ww0 = w0a + dw; ww0 = (ww0 < 0) ? 1 : (ww0 > 63 ? 62 : ww0);
        int hh1 = h1a + dh; hh1 = (hh1 < 0) ? 1 : (hh1 > 63 ? 62 : hh1);
        int ww1 = w1a + dw; ww1 = (ww1 < 0) ? 1 : (ww1 > 63 ? 62 : ww1);
        const unsigned short* gA0 = srcB + (size_t)((hh0 << 6) + ww0) * 256 + lko;
        const unsigned short* gA1 = srcB + (size_t)((hh1 << 6) + ww1) * 256 + lko;
#pragma unroll
        for (int c = 0; c < 8; ++c) {
            __syncthreads();  // previous iter's frag reads done before overwrite
            gload16(gA0, ldsA0);
            gload16(gA1, ldsA1);
            gload16(gB0, ldsB0);
            gload16(gB1, ldsB1);
            gA0 += 32; gA1 += 32; gB0 += 32; gB1 += 32;
            __syncthreads();  // vmcnt(0) drain -> data visible

            bf16x8 af[4], bfr[4];
#pragma unroll
            for (int i = 0; i < 4; ++i) af[i] = *(const bf16x8*)&As[(rm + i * 16 + fr) * 32 + kg];
#pragma unroll
            for (int j = 0; j < 4; ++j) bfr[j] = *(const bf16x8*)&Bs[(cn + j * 16 + fr) * 32 + kg];
#pragma unroll
            for (int i = 0; i < 4; ++i)
#pragma unroll
                for (int j = 0; j < 4; ++j)
                    acc[i][j] = __builtin_amdgcn_mfma_f32_16x16x32_bf16(af[i], bfr[j], acc[i][j], 0, 0, 0);
        }
    }

    // epilogue: C/D layout col=lane&15, row=(lane>>4)*4+reg
    const int rbase = (lane >> 4) * 4;
    const int col = lane & 15;
    float bv[4];
#pragma unroll
    for (int j = 0; j < 4; ++j) {
        int n = n0 + cn + j * 16 + col;
        if (BIAS_MODE == 2)      bv[j] = ldg_elem(bias, b * 256 + n, in_bf);
        else if (BIAS_MODE == 3) bv[j] = ldg_elem(bias, n, in_bf);
        else                     bv[j] = 0.f;
    }
#pragma unroll
    for (int i = 0; i < 4; ++i) {
#pragma unroll
        for (int rr = 0; rr < 4; ++rr) {
            int m = m0 + rm + i * 16 + rbase + rr;
            size_t rowoff = ((size_t)b * 4096 + m) * 256;
#pragma unroll
            for (int j = 0; j < 4; ++j) {
                int n = n0 + cn + j * 16 + col;
                float val = acc[i][j][rr] + bv[j];
                if (OUT_F32) ((float*)dst)[rowoff + n] = val;
                else         ((unsigned short*)dst)[rowoff + n] = f2bf(val);
            }
        }
    }
}

// ---------------- register-staging GEMM (small-ws fallback conv1 only) ----------------
template <int KSLICES, bool PER_SAMPLE_W, int BIAS_MODE, bool IS3X3, bool SRC_ADAPT, bool OUT_F32>
__global__ __launch_bounds__(256) void gemm_conv(const void* __restrict__ src,
                                                 const int* __restrict__ flag,
                                                 const unsigned short* __restrict__ wT,
                                                 const void* __restrict__ bias,
                                                 void* __restrict__ dst) {
    constexpr int KTOT = KSLICES * 256;
    __shared__ unsigned short As[128][40];
    __shared__ unsigned short Bs[128][40];

    const bool in_bf = (SRC_ADAPT || BIAS_MODE >= 2) ? (*flag != 0) : true;
    const int t = threadIdx.x;
    const int b = blockIdx.z;
    const int m0 = blockIdx.x * 128;
    const int n0 = blockIdx.y * 128;
    const size_t srcOfs = (size_t)b * (4096 * 256);
    const unsigned short* wB = wT + (PER_SAMPLE_W ? (size_t)b * 256 * KTOT : (size_t)0);

    f32x4 acc[4][4];
#pragma unroll
    for (int i = 0; i < 4; ++i)
#pragma unroll
        for (int j = 0; j < 4; ++j) acc[i][j] = (f32x4){0.f, 0.f, 0.f, 0.f};

    const int lane = t & 63;
    const int wave = t >> 6;
    const int rm = (wave >> 1) * 64;
    const int cn = (wave & 1) * 64;
    const int fr = lane & 15;
    const int kg = (lane >> 4) * 8;

    for (int kk = 0; kk < KTOT / 32; ++kk) {
        const int k0 = kk * 32;
        const int s = k0 >> 8;
        const int ci0 = k0 & 255;
        const int dh = IS3X3 ? (s / 3) - 1 : 0;
        const int dw = IS3X3 ? (s % 3) - 1 : 0;
        __syncthreads();
#pragma unroll
        for (int cc = 0; cc < 2; ++cc) {
            int ch = t + cc * 256;
            int r = ch >> 2;
            int ko = (ch & 3) << 3;
            int m = m0 + r;
            int h = m >> 6, w = m & 63;
            if (IS3X3) {
                h += dh; h = (h < 0) ? 1 : (h > 63 ? 62 : h);
                w += dw; w = (w < 0) ? 1 : (w > 63 ? 62 : w);
            }
            size_t eidx = srcOfs + (size_t)((h << 6) + w) * 256 + ci0 + ko;
            if (!SRC_ADAPT || in_bf) {
                uint4 v = *(const uint4*)((const unsigned short*)src + eidx);
                *(uint4*)&As[r][ko] = v;
            } else {
                const float* sf = (const float*)src + eidx;
                float4 f0 = *(const float4*)sf;
                float4 f1 = *(const float4*)(sf + 4);
                uint4 v;
                v.x = (unsigned int)f2bf(f0.x) | ((unsigned int)f2bf(f0.y) << 16);
                v.y = (unsigned int)f2bf(f0.z) | ((unsigned int)f2bf(f0.w) << 16);
                v.z = (unsigned int)f2bf(f1.x) | ((unsigned int)f2bf(f1.y) << 16);
                v.w = (unsigned int)f2bf(f1.z) | ((unsigned int)f2bf(f1.w) << 16);
                *(uint4*)&As[r][ko] = v;
            }
        }
#pragma unroll
        for (int cc = 0; cc < 2; ++cc) {
            int ch = t + cc * 256;
            int n = ch >> 2;
            int ko = (ch & 3) << 3;
            uint4 v = *(const uint4*)(wB + (size_t)(n0 + n) * KTOT + k0 + ko);
            *(uint4*)&Bs[n][ko] = v;
        }
        __syncthreads();

        bf16x8 af[4], bfr[4];
#pragma unroll
        for (int i = 0; i < 4; ++i) af[i] = *(const bf16x8*)&As[rm + i * 16 + fr][kg];
#pragma unroll
        for (int j = 0; j < 4; ++j) bfr[j] = *(const bf16x8*)&Bs[cn + j * 16 + fr][kg];
#pragma unroll
        for (int i = 0; i < 4; ++i)
#pragma unroll
            for (int j = 0; j < 4; ++j)
                acc[i][j] = __builtin_amdgcn_mfma_f32_16x16x32_bf16(af[i], bfr[j], acc[i][j], 0, 0, 0);
    }

    const int rbase = (lane >> 4) * 4;
    const int col = lane & 15;
    float bv[4];
#pragma unroll
    for (int j = 0; j < 4; ++j) {
        int n = n0 + cn + j * 16 + col;
        if (BIAS_MODE == 1)      bv[j] = ((const float*)bias)[b * 256 + n];
        else if (BIAS_MODE == 2) bv[j] = ldg_elem(bias, b * 256 + n, in_bf);
        else if (BIAS_MODE == 3) bv[j] = ldg_elem(bias, n, in_bf);
        else                     bv[j] = 0.f;
    }
#pragma unroll
    for (int i = 0; i < 4; ++i) {
#pragma unroll
        for (int rr = 0; rr < 4; ++rr) {
            int m = m0 + rm + i * 16 + rbase + rr;
            size_t rowoff = ((size_t)b * 4096 + m) * 256;
#pragma unroll
            for (int j = 0; j < 4; ++j) {
                int n = n0 + cn + j * 16 + col;
                float val = acc[i][j][rr] + bv[j];
                if (OUT_F32) ((float*)dst)[rowoff + n] = val;
                else         ((unsigned short*)dst)[rowoff + n] = f2bf(val);
            }
        }
    }
}

extern "C" void kernel_launch(void* const* d_in, const int* in_sizes, int n_in,
                              void* d_out, int out_size, void* d_ws, size_t ws_size,
                              hipStream_t stream) {
    const void* x    = d_in[0];
    const void* dk   = d_in[1];
    const void* pk   = d_in[2];
    const void* bias = d_in[3];
    const void* cw   = d_in[4];
    const void* cb   = d_in[5];

    // layout:
    //   0        flag
    //   1024     mean    16 KB
    //   17408    rstd    16 KB
    //   33792    negcorr 16 KB (fallback only)
    //   65536    pkT     2,097,152
    //   2162688  cwT     1,179,648
    //   3342336  dkT     18,874,368 (ends 22,216,704)
    //   big path:  22216704 xn 33,554,432 (ends 55,771,136); y2 overlays xn
    //   small path: y2 overlays dkT at 3342336 (ends 36,896,768)
    const size_t NEED_SMALL = 36896768u;
    const size_t NEED_BIG   = 55771136u;
    if (ws_size < NEED_SMALL) return;  // diagnostic: out stays 0 -> absmax ~4.78
    const bool big = (ws_size >= NEED_BIG);

    char* ws = (char*)d_ws;
    int*   flagp   = (int*)ws;
    float* meanp   = (float*)(ws + 1024);
    float* rstdp   = (float*)(ws + 17408);
    float* negcorr = (float*)(ws + 33792);
    unsigned short* pkT = (unsigned short*)(ws + 65536);
    unsigned short* cwT = (unsigned short*)(ws + 2162688);
    unsigned short* dkT = (unsigned short*)(ws + 3342336);
    unsigned short* xn  = (unsigned short*)(ws + 22216704);
    unsigned short* y2  = big ? xn : dkT;  // overlay region dead by the time y2 is written
    unsigned short* y1  = (unsigned short*)d_out;  // bf16 scratch inside fp32 out buffer

    detect_dtype<<<1, 256, 0, stream>>>((const unsigned short*)x, flagp);
    init_stats<<<32, 256, 0, stream>>>(meanp);
    norm_partial<<<dim3(16, 16), 256, 0, stream>>>(x, flagp, meanp, rstdp);
    norm_finalize<<<16, 256, 0, stream>>>(meanp, rstdp);

    transpose_wk<false><<<dim3(16, 4, 4), 256, 0, stream>>>(pk, flagp, pkT, 1, 65536L, 256, nullptr);
    transpose_wk<false><<<dim3(9, 4, 4), 256, 0, stream>>>(cw, flagp, cwT, 9, 0L, 2304, nullptr);

    if (big) {
        transpose_wk<false><<<dim3(144, 4, 4), 256, 0, stream>>>(dk, flagp, dkT, 9, 589824L, 2304, nullptr);
        norm_apply<<<8192, 256, 0, stream>>>(x, flagp, meanp, rstdp, xn);
        // conv1: per-sample 3x3 on xn (bf16) via DMA staging -> y1 (bf16 in d_out)
        gemm_conv_dma<9, true, 0, true, false><<<dim3(32, 2, 16), 256, 0, stream>>>(xn, flagp, dkT, nullptr, y1);
    } else {
        transpose_wk<true><<<dim3(144, 4, 4), 256, 0, stream>>>(dk, flagp, dkT, 9, 589824L, 2304, rstdp);
        corr_kernel<<<dim3(16, 64), 256, 0, stream>>>(dkT, meanp, negcorr);
        // conv1: folded norm, register staging on raw x (adaptive dtype)
        gemm_conv<9, true, 1, true, true, false><<<dim3(32, 2, 16), 256, 0, stream>>>(x, flagp, dkT, negcorr, y1);
    }

    // pointwise 1x1 + per-sample bias -> y2 (bf16), DMA staging
    gemm_conv_dma<1, true, 2, false, false><<<dim3(32, 2, 16), 256, 0, stream>>>(y1, flagp, pkT, bias, y2);
    // shared 3x3 + conv_b -> out (fp32), DMA staging
    gemm_conv_dma<9, false, 3, true, true><<<dim3(32, 2, 16), 256, 0, stream>>>(y2, flagp, cwT, cb, d_out);
}

// Round 5
// 390.583 us; speedup vs baseline: 1.5055x; 1.2409x over previous
//
#include <hip/hip_runtime.h>

// AdaConv: instance-norm -> per-sample 3x3 conv -> per-sample 1x1 conv + bias
//          -> shared 3x3 conv. Reflect-pad(1), NHWC. B=16, H=W=64, C=256.
// Inputs fp32 (runtime-detected vs bf16); OUTPUT FP32. Internal compute bf16 MFMA.
// Big-ws path: norm_apply -> xn(bf16); GEMMs use global_load_lds DMA, BK=64,
// XOR-swizzled LDS chunks (DMA-compatible: permutes which global 16B chunk each
// lane fetches within the same 128B segment).

typedef __bf16 bf16x8 __attribute__((ext_vector_type(8)));
typedef float f32x4 __attribute__((ext_vector_type(4)));

__device__ __forceinline__ float bf2f(unsigned short v) {
    return __uint_as_float(((unsigned int)v) << 16);
}
__device__ __forceinline__ unsigned short f2bf(float f) {
    unsigned int u = __float_as_uint(f);
    unsigned int r = (u + 0x7FFFu + ((u >> 16) & 1u)) >> 16;  // RNE
    return (unsigned short)r;
}
__device__ __forceinline__ float ldg_elem(const void* p, size_t idx, bool isbf) {
    return isbf ? bf2f(((const unsigned short*)p)[idx]) : ((const float*)p)[idx];
}

// async global->LDS DMA, 16B per lane; LDS dest = wave-uniform base + lane*16
__device__ __forceinline__ void gload16(const void* g, void* l) {
    __builtin_amdgcn_global_load_lds(
        (__attribute__((address_space(1))) void*)(unsigned long long)g,
        (__attribute__((address_space(3))) void*)(unsigned long long)l,
        16, 0, 0);
}

// ---------------- dtype detection ----------------
__global__ void detect_dtype(const unsigned short* __restrict__ x, int* __restrict__ flag) {
    __shared__ int wild;
    if (threadIdx.x == 0) wild = 0;
    __syncthreads();
    int cnt = 0;
    for (int i = 0; i < 16; ++i) {
        float a = fabsf(bf2f(x[threadIdx.x * 16 + i]));
        if (!(a < 64.f) || (a != 0.f && a < 1e-5f)) cnt++;  // catches NaN/Inf too
    }
    atomicAdd(&wild, cnt);
    __syncthreads();
    if (threadIdx.x == 0) *flag = (wild > 512) ? 0 : 1;  // 0 = fp32, 1 = bf16
}

// ---------------- instance-norm stats ----------------

__global__ void init_stats(float* s) { s[blockIdx.x * 256 + threadIdx.x] = 0.f; }

// grid (16 batches, 64 spatial chunks), block 256 (one lane per channel)
__global__ void norm_partial(const void* __restrict__ x, const int* __restrict__ flag,
                             float* __restrict__ ssum, float* __restrict__ ssq) {
    const bool isbf = (*flag != 0);
    const int b = blockIdx.x, chunk = blockIdx.y, c = threadIdx.x;
    const size_t base = ((size_t)(b * 4096 + chunk * 64)) * 256 + c;
    float s = 0.f, q = 0.f;
    for (int i = 0; i < 64; ++i) {
        float v = ldg_elem(x, base + (size_t)i * 256, isbf);
        s += v; q += v * v;
    }
    atomicAdd(&ssum[b * 256 + c], s);
    atomicAdd(&ssq[b * 256 + c], q);
}

__global__ void norm_finalize(float* ssum, float* ssq) {
    int i = blockIdx.x * 256 + threadIdx.x;
    float mean = ssum[i] * (1.f / 4096.f);
    float var  = ssq[i]  * (1.f / 4096.f) - mean * mean;
    ssum[i] = mean;
    ssq[i]  = rsqrtf(var + 1e-3f);
}

// normalize x -> bf16 xn. grid 8192 x 256, 8 elems/thread.
__global__ void norm_apply(const void* __restrict__ x, const int* __restrict__ flag,
                           const float* __restrict__ mean, const float* __restrict__ rstd,
                           unsigned short* __restrict__ xn) {
    const bool isbf = (*flag != 0);
    size_t e = ((size_t)blockIdx.x * 256 + threadIdx.x) * 8;
    int c0 = (int)(e & 255);
    int bc = (int)(e >> 20) * 256 + c0;
    float v[8];
    if (isbf) {
        uint4 raw = *(const uint4*)((const unsigned short*)x + e);
        unsigned int rr[4] = {raw.x, raw.y, raw.z, raw.w};
#pragma unroll
        for (int i = 0; i < 4; ++i) {
            v[2 * i]     = bf2f((unsigned short)(rr[i] & 0xFFFF));
            v[2 * i + 1] = bf2f((unsigned short)(rr[i] >> 16));
        }
    } else {
        float4 f0 = *(const float4*)((const float*)x + e);
        float4 f1 = *(const float4*)((const float*)x + e + 4);
        v[0] = f0.x; v[1] = f0.y; v[2] = f0.z; v[3] = f0.w;
        v[4] = f1.x; v[5] = f1.y; v[6] = f1.z; v[7] = f1.w;
    }
    unsigned int o[4];
#pragma unroll
    for (int i = 0; i < 4; ++i) {
        unsigned short lo = f2bf((v[2 * i]     - mean[bc + 2 * i])     * rstd[bc + 2 * i]);
        unsigned short hi = f2bf((v[2 * i + 1] - mean[bc + 2 * i + 1]) * rstd[bc + 2 * i + 1]);
        o[i] = (unsigned int)lo | ((unsigned int)hi << 16);
    }
    uint4 out; out.x = o[0]; out.y = o[1]; out.z = o[2]; out.w = o[3];
    *(uint4*)(xn + e) = out;
}

// ---------------- weight transpose: [slice][ci][co] -> [b][co][s*256+ci] ----------------
// grid (nslices, 4, 4) of 64x64 tiles, block 256. Vectorized loads, packed writes.
template <bool SCALE>
__global__ void transpose_wk(const void* __restrict__ src, const int* __restrict__ flag,
                             unsigned short* __restrict__ dst,
                             int s_per, long dstBStride, int coStride,
                             const float* __restrict__ rstd) {
    __shared__ unsigned short tile[64][66];
    const bool isbf = (*flag != 0);
    const int sl = blockIdx.x;
    const int b = sl / s_per;
    const size_t dbase = (size_t)b * (size_t)dstBStride + (size_t)(sl % s_per) * 256;
    const int ci0 = blockIdx.y * 64, co0 = blockIdx.z * 64;
    const int t = threadIdx.x;
    // load: 4 iters; each thread 4 consecutive co of row r
    const int co4 = (t & 15) * 4;
    const int r0 = t >> 4;  // 0..15
#pragma unroll
    for (int i = 0; i < 4; ++i) {
        int r = r0 + i * 16;
        size_t sidx = (size_t)sl * 65536 + (size_t)(ci0 + r) * 256 + co0 + co4;
        if (isbf) {
            ushort4 v = *(const ushort4*)((const unsigned short*)src + sidx);
            tile[r][co4] = v.x; tile[r][co4 + 1] = v.y;
            tile[r][co4 + 2] = v.z; tile[r][co4 + 3] = v.w;
        } else {
            float4 v = *(const float4*)((const float*)src + sidx);
            tile[r][co4] = f2bf(v.x); tile[r][co4 + 1] = f2bf(v.y);
            tile[r][co4 + 2] = f2bf(v.z); tile[r][co4 + 3] = f2bf(v.w);
        }
    }
    __syncthreads();
    // write: 8 iters; each thread packs ci pair, 32 lanes -> 128B contiguous
    const int cip = (t & 31) * 2;
    const int cob = t >> 5;  // 0..7
    float s0 = 1.f, s1 = 1.f;
    if (SCALE) { s0 = rstd[b * 256 + ci0 + cip]; s1 = rstd[b * 256 + ci0 + cip + 1]; }
#pragma unroll
    for (int i = 0; i < 8; ++i) {
        int co = cob + i * 8;
        unsigned short lo = tile[cip][co], hi = tile[cip + 1][co];
        if (SCALE) { lo = f2bf(bf2f(lo) * s0); hi = f2bf(bf2f(hi) * s1); }
        *(unsigned int*)(dst + dbase + (size_t)(co0 + co) * coStride + ci0 + cip) =
            (unsigned int)lo | ((unsigned int)hi << 16);
    }
}

// ---------------- correction bias (small-ws fallback): negcorr[b][co] ----------------
__global__ void corr_kernel(const unsigned short* __restrict__ dkT,
                            const float* __restrict__ mean,
                            float* __restrict__ negcorr) {
    const int b = blockIdx.x;
    const int lane = threadIdx.x & 63;
    const int co = blockIdx.y * 4 + (threadIdx.x >> 6);
    const unsigned short* wp = dkT + (size_t)(b * 256 + co) * 2304;
    const float* mb = mean + b * 256;
    const int ci0 = (lane & 31) * 8;
    float4 ma = *(const float4*)(mb + ci0);
    float4 mc = *(const float4*)(mb + ci0 + 4);
    float mm[8] = {ma.x, ma.y, ma.z, ma.w, mc.x, mc.y, mc.z, mc.w};
    float sum = 0.f;
#pragma unroll
    for (int c = 0; c < 5; ++c) {
        int k = c * 512 + lane * 8;
        if (k < 2304) {
            uint4 w = *(const uint4*)(wp + k);
            unsigned int wsv[4] = {w.x, w.y, w.z, w.w};
#pragma unroll
            for (int j = 0; j < 4; ++j) {
                sum += bf2f((unsigned short)(wsv[j] & 0xFFFF)) * mm[2 * j];
                sum += bf2f((unsigned short)(wsv[j] >> 16)) * mm[2 * j + 1];
            }
        }
    }
#pragma unroll
    for (int off = 32; off > 0; off >>= 1) sum += __shfl_down(sum, off);
    if (lane == 0) negcorr[b * 256 + co] = -sum;
}

// ---------------- implicit-GEMM conv, DMA staging, BK=64, XOR-swizzle ----------------
// src MUST be bf16. Tile 128x128. LDS As/Bs[128][64] unpadded; chunk c of row r
// holds global chunk (c ^ (r&7)) -> frag reads spread across 8 bank groups.
// BIAS_MODE: 0=none, 2=input per-sample, 3=input shared.
template <int KSLICES, bool PER_SAMPLE_W, int BIAS_MODE, bool IS3X3, bool OUT_F32>
__global__ __launch_bounds__(256) void gemm_conv_dma(const unsigned short* __restrict__ src,
                                                     const int* __restrict__ flag,
                                                     const unsigned short* __restrict__ wT,
                                                     const void* __restrict__ bias,
                                                     void* __restrict__ dst) {
    constexpr int KTOT = KSLICES * 256;
    __shared__ unsigned short As[128 * 64];
    __shared__ unsigned short Bs[128 * 64];

    const int t = threadIdx.x;
    const int lane = t & 63;
    const int wave = t >> 6;
    const int b = blockIdx.z;
    const int m0 = blockIdx.x * 128;
    const int n0 = blockIdx.y * 128;
    const unsigned short* srcB = src + (size_t)b * (4096 * 256);
    const unsigned short* wB = wT + (PER_SAMPLE_W ? (size_t)b * 256 * KTOT : (size_t)0);
    const bool in_bf = (BIAS_MODE >= 2) ? (*flag != 0) : true;

    f32x4 acc[4][4];
#pragma unroll
    for (int i = 0; i < 4; ++i)
#pragma unroll
        for (int j = 0; j < 4; ++j) acc[i][j] = (f32x4){0.f, 0.f, 0.f, 0.f};

    // staging geometry: per issue, 64 lanes cover 8 rows x 8 chunks (16B each).
    const int lr = lane >> 3;          // row within 8
    const int cidx = lane & 7;         // chunk slot in LDS
    const int swz = ((cidx ^ lr) << 3);  // global element offset (swizzled chunk)

    // per-wave rows: A rows [wave*32, +32) via 4 issues of 8; same for B.
    int hA[4], wA[4];
    const unsigned short* gB[4];
    unsigned short* ldsA[4];
    unsigned short* ldsB[4];
#pragma unroll
    for (int c = 0; c < 4; ++c) {
        int r = wave * 32 + c * 8;          // wave-uniform row base
        int m = m0 + r + lr;
        hA[c] = m >> 6; wA[c] = m & 63;
        gB[c] = wB + (size_t)(n0 + r + lr) * KTOT + swz;
        ldsA[c] = As + r * 64;
        ldsB[c] = Bs + r * 64;
    }

    const int fr = lane & 15;
    const int quad = lane >> 4;
    const int rm = (wave >> 1) * 64;
    const int cn = (wave & 1) * 64;
    const int fsw = fr & 7;

    for (int s = 0; s < KSLICES; ++s) {
        const int dh = IS3X3 ? (s / 3) - 1 : 0;
        const int dw = IS3X3 ? (s % 3) - 1 : 0;
        const unsigned short* gA[4];
#pragma unroll
        for (int c = 0; c < 4; ++c) {
            int hh = hA[c] + dh; hh = (hh < 0) ? 1 : (hh > 63 ? 62 : hh);  // reflect 1
            int ww = wA[c] + dw; ww = (ww < 0) ? 1 : (ww > 63 ? 62 : ww);
            gA[c] = srcB + (size_t)((hh << 6) + ww) * 256 + swz;
        }
        const int kbase = s * 256;
#pragma unroll
        for (int cc = 0; cc < 4; ++cc) {
            __syncthreads();  // previous iter's frag reads done before overwrite
#pragma unroll
            for (int c = 0; c < 4; ++c) {
                gload16(gA[c] + cc * 64, ldsA[c]);
                gload16(gB[c] + kbase + cc * 64, ldsB[c]);
            }
            __syncthreads();  // drain -> data visible

#pragma unroll
            for (int step = 0; step < 2; ++step) {
                const int ks = ((quad + step * 4) ^ fsw) << 3;  // swizzled chunk offset
                bf16x8 af[4], bfr[4];
#pragma unroll
                for (int i = 0; i < 4; ++i)
                    af[i] = *(const bf16x8*)&As[(rm + i * 16 + fr) * 64 + ks];
#pragma unroll
                for (int j = 0; j < 4; ++j)
                    bfr[j] = *(const bf16x8*)&Bs[(cn + j * 16 + fr) * 64 + ks];
#pragma unroll
                for (int i = 0; i < 4; ++i)
#pragma unroll
                    for (int j = 0; j < 4; ++j)
                        acc[i][j] = __builtin_amdgcn_mfma_f32_16x16x32_bf16(af[i], bfr[j], acc[i][j], 0, 0, 0);
            }
        }
    }

    // epilogue: C/D layout col=lane&15, row=(lane>>4)*4+reg
    const int rbase = quad * 4;
    const int col = fr;
    float bv[4];
#pragma unroll
    for (int j = 0; j < 4; ++j) {
        int n = n0 + cn + j * 16 + col;
        if (BIAS_MODE == 2)      bv[j] = ldg_elem(bias, b * 256 + n, in_bf);
        else if (BIAS_MODE == 3) bv[j] = ldg_elem(bias, n, in_bf);
        else                     bv[j] = 0.f;
    }
#pragma unroll
    for (int i = 0; i < 4; ++i) {
#pragma unroll
        for (int rr = 0; rr < 4; ++rr) {
            int m = m0 + rm + i * 16 + rbase + rr;
            size_t rowoff = ((size_t)b * 4096 + m) * 256;
#pragma unroll
            for (int j = 0; j < 4; ++j) {
                int n = n0 + cn + j * 16 + col;
                float val = acc[i][j][rr] + bv[j];
                if (OUT_F32) ((float*)dst)[rowoff + n] = val;
                else         ((unsigned short*)dst)[rowoff + n] = f2bf(val);
            }
        }
    }
}

// ---------------- register-staging GEMM (small-ws fallback conv1 only) ----------------
template <int KSLICES, bool PER_SAMPLE_W, int BIAS_MODE, bool IS3X3, bool SRC_ADAPT, bool OUT_F32>
__global__ __launch_bounds__(256) void gemm_conv(const void* __restrict__ src,
                                                 const int* __restrict__ flag,
                                                 const unsigned short* __restrict__ wT,
                                                 const void* __restrict__ bias,
                                                 void* __restrict__ dst) {
    constexpr int KTOT = KSLICES * 256;
    __shared__ unsigned short As[128][40];
    __shared__ unsigned short Bs[128][40];

    const bool in_bf = (SRC_ADAPT || BIAS_MODE >= 2) ? (*flag != 0) : true;
    const int t = threadIdx.x;
    const int b = blockIdx.z;
    const int m0 = blockIdx.x * 128;
    const int n0 = blockIdx.y * 128;
    const size_t srcOfs = (size_t)b * (4096 * 256);
    const unsigned short* wB = wT + (PER_SAMPLE_W ? (size_t)b * 256 * KTOT : (size_t)0);

    f32x4 acc[4][4];
#pragma unroll
    for (int i = 0; i < 4; ++i)
#pragma unroll
        for (int j = 0; j < 4; ++j) acc[i][j] = (f32x4){0.f, 0.f, 0.f, 0.f};

    const int lane = t & 63;
    const int wave = t >> 6;
    const int rm = (wave >> 1) * 64;
    const int cn = (wave & 1) * 64;
    const int fr = lane & 15;
    const int kg = (lane >> 4) * 8;

    for (int kk = 0; kk < KTOT / 32; ++kk) {
        const int k0 = kk * 32;
        const int s = k0 >> 8;
        const int ci0 = k0 & 255;
        const int dh = IS3X3 ? (s / 3) - 1 : 0;
        const int dw = IS3X3 ? (s % 3) - 1 : 0;
        __syncthreads();
#pragma unroll
        for (int cc = 0; cc < 2; ++cc) {
            int ch = t + cc * 256;
            int r = ch >> 2;
            int ko = (ch & 3) << 3;
            int m = m0 + r;
            int h = m >> 6, w = m & 63;
            if (IS3X3) {
                h += dh; h = (h < 0) ? 1 : (h > 63 ? 62 : h);
                w += dw; w = (w < 0) ? 1 : (w > 63 ? 62 : w);
            }
            size_t eidx = srcOfs + (size_t)((h << 6) + w) * 256 + ci0 + ko;
            if (!SRC_ADAPT || in_bf) {
                uint4 v = *(const uint4*)((const unsigned short*)src + eidx);
                *(uint4*)&As[r][ko] = v;
            } else {
                const float* sf = (const float*)src + eidx;
                float4 f0 = *(const float4*)sf;
                float4 f1 = *(const float4*)(sf + 4);
                uint4 v;
                v.x = (unsigned int)f2bf(f0.x) | ((unsigned int)f2bf(f0.y) << 16);
                v.y = (unsigned int)f2bf(f0.z) | ((unsigned int)f2bf(f0.w) << 16);
                v.z = (unsigned int)f2bf(f1.x) | ((unsigned int)f2bf(f1.y) << 16);
                v.w = (unsigned int)f2bf(f1.z) | ((unsigned int)f2bf(f1.w) << 16);
                *(uint4*)&As[r][ko] = v;
            }
        }
#pragma unroll
        for (int cc = 0; cc < 2; ++cc) {
            int ch = t + cc * 256;
            int n = ch >> 2;
            int ko = (ch & 3) << 3;
            uint4 v = *(const uint4*)(wB + (size_t)(n0 + n) * KTOT + k0 + ko);
            *(uint4*)&Bs[n][ko] = v;
        }
        __syncthreads();

        bf16x8 af[4], bfr[4];
#pragma unroll
        for (int i = 0; i < 4; ++i) af[i] = *(const bf16x8*)&As[rm + i * 16 + fr][kg];
#pragma unroll
        for (int j = 0; j < 4; ++j) bfr[j] = *(const bf16x8*)&Bs[cn + j * 16 + fr][kg];
#pragma unroll
        for (int i = 0; i < 4; ++i)
#pragma unroll
            for (int j = 0; j < 4; ++j)
                acc[i][j] = __builtin_amdgcn_mfma_f32_16x16x32_bf16(af[i], bfr[j], acc[i][j], 0, 0, 0);
    }

    const int rbase = (lane >> 4) * 4;
    const int col = lane & 15;
    float bv[4];
#pragma unroll
    for (int j = 0; j < 4; ++j) {
        int n = n0 + cn + j * 16 + col;
        if (BIAS_MODE == 1)      bv[j] = ((const float*)bias)[b * 256 + n];
        else if (BIAS_MODE == 2) bv[j] = ldg_elem(bias, b * 256 + n, in_bf);
        else if (BIAS_MODE == 3) bv[j] = ldg_elem(bias, n, in_bf);
        else                     bv[j] = 0.f;
    }
#pragma unroll
    for (int i = 0; i < 4; ++i) {
#pragma unroll
        for (int rr = 0; rr < 4; ++rr) {
            int m = m0 + rm + i * 16 + rbase + rr;
            size_t rowoff = ((size_t)b * 4096 + m) * 256;
#pragma unroll
            for (int j = 0; j < 4; ++j) {
                int n = n0 + cn + j * 16 + col;
                float val = acc[i][j][rr] + bv[j];
                if (OUT_F32) ((float*)dst)[rowoff + n] = val;
                else         ((unsigned short*)dst)[rowoff + n] = f2bf(val);
            }
        }
    }
}

extern "C" void kernel_launch(void* const* d_in, const int* in_sizes, int n_in,
                              void* d_out, int out_size, void* d_ws, size_t ws_size,
                              hipStream_t stream) {
    const void* x    = d_in[0];
    const void* dk   = d_in[1];
    const void* pk   = d_in[2];
    const void* bias = d_in[3];
    const void* cw   = d_in[4];
    const void* cb   = d_in[5];

    // layout:
    //   0        flag
    //   1024     mean    16 KB
    //   17408    rstd    16 KB
    //   33792    negcorr 16 KB (fallback only)
    //   65536    pkT     2,097,152
    //   2162688  cwT     1,179,648
    //   3342336  dkT     18,874,368 (ends 22,216,704)
    //   big path:  22216704 xn 33,554,432 (ends 55,771,136); y2 overlays xn
    //   small path: y2 overlays dkT at 3342336 (ends 36,896,768)
    const size_t NEED_SMALL = 36896768u;
    const size_t NEED_BIG   = 55771136u;
    if (ws_size < NEED_SMALL) return;  // diagnostic: out stays 0 -> absmax ~4.78
    const bool big = (ws_size >= NEED_BIG);

    char* ws = (char*)d_ws;
    int*   flagp   = (int*)ws;
    float* meanp   = (float*)(ws + 1024);
    float* rstdp   = (float*)(ws + 17408);
    float* negcorr = (float*)(ws + 33792);
    unsigned short* pkT = (unsigned short*)(ws + 65536);
    unsigned short* cwT = (unsigned short*)(ws + 2162688);
    unsigned short* dkT = (unsigned short*)(ws + 3342336);
    unsigned short* xn  = (unsigned short*)(ws + 22216704);
    unsigned short* y2  = big ? xn : dkT;  // overlay region dead when y2 written
    unsigned short* y1  = (unsigned short*)d_out;  // bf16 scratch inside fp32 out buffer

    detect_dtype<<<1, 256, 0, stream>>>((const unsigned short*)x, flagp);
    init_stats<<<32, 256, 0, stream>>>(meanp);
    norm_partial<<<dim3(16, 64), 256, 0, stream>>>(x, flagp, meanp, rstdp);
    norm_finalize<<<16, 256, 0, stream>>>(meanp, rstdp);

    transpose_wk<false><<<dim3(16, 4, 4), 256, 0, stream>>>(pk, flagp, pkT, 1, 65536L, 256, nullptr);
    transpose_wk<false><<<dim3(9, 4, 4), 256, 0, stream>>>(cw, flagp, cwT, 9, 0L, 2304, nullptr);

    if (big) {
        transpose_wk<false><<<dim3(144, 4, 4), 256, 0, stream>>>(dk, flagp, dkT, 9, 589824L, 2304, nullptr);
        norm_apply<<<8192, 256, 0, stream>>>(x, flagp, meanp, rstdp, xn);
        // conv1: per-sample 3x3 on xn (bf16) via DMA staging -> y1 (bf16 in d_out)
        gemm_conv_dma<9, true, 0, true, false><<<dim3(32, 2, 16), 256, 0, stream>>>(xn, flagp, dkT, nullptr, y1);
    } else {
        transpose_wk<true><<<dim3(144, 4, 4), 256, 0, stream>>>(dk, flagp, dkT, 9, 589824L, 2304, rstdp);
        corr_kernel<<<dim3(16, 64), 256, 0, stream>>>(dkT, meanp, negcorr);
        // conv1: folded norm, register staging on raw x (adaptive dtype)
        gemm_conv<9, true, 1, true, true, false><<<dim3(32, 2, 16), 256, 0, stream>>>(x, flagp, dkT, negcorr, y1);
    }

    // pointwise 1x1 + per-sample bias -> y2 (bf16), DMA staging
    gemm_conv_dma<1, true, 2, false, false><<<dim3(32, 2, 16), 256, 0, stream>>>(y1, flagp, pkT, bias, y2);
    // shared 3x3 + conv_b -> out (fp32), DMA staging
    gemm_conv_dma<9, false, 3, true, true><<<dim3(32, 2, 16), 256, 0, stream>>>(y2, flagp, cwT, cb, d_out);
}